// Round 4
// baseline (783.090 us; speedup 1.0000x reference)
//
#include <hip/hip_runtime.h>
#include <hip/hip_bf16.h>

// MSAttention: Res2Net inconv + 3x(dwconv+pwconv+BN) + per-(scale,head) self-attention + out-proj.
// Round 4 model (explains R0-R3 with zero kernel bugs):
//   inputs f32 (PROVEN: R2==R3 bit-identical under dtype detector), output buffer f32
//   (harness doc: reference's output dtype = f32; comparison quantizes to bf16 => R0's
//   bf16-clean 8.875; R2/R3's 12.03 = bf16-halfwords packed into an f32 buffer).
// Layouts:
//   Y   f32 [B][512][N]   channel-major (scale s occupies channels s*128..)
//   O   f32 [B][N][512]   attention output (n-major rows feed out-proj)
//   tmp f32 [B][128][N]   dwconv output, ALIASED on O (disjoint in time: tmp last read
//                         = pwconv s=3, O first write = attn)
// ws usage: 16 MB + 16 MB = 32 MB (R2 ran this exact footprint to completion).

#define DIMM 512
#define NTOK 1024
#define CC   128
#define DD   32
#define BB   8
#define EPSB 1e-5f
#define SCALE_ATT 0.17677669529663687f  // 32^-0.5
#define TJ 128

// ---------------- K1: inconv (1x1) GEMM + BN1 ----------------
// Y[b][o][n] = BN1( sum_c w_in[o][c] * x[b][n][c] )
__global__ __launch_bounds__(256) void k_inconv(
    const float* __restrict__ x,     // [B][N][DIM]
    const float* __restrict__ w_in,  // [DIM][DIM]
    const float* __restrict__ g1, const float* __restrict__ b1,
    const float* __restrict__ m1, const float* __restrict__ v1,
    float* __restrict__ Y)
{
    __shared__ float Wt[64][33];
    __shared__ float Xt[64][33];
    const int b  = blockIdx.z;
    const int o0 = blockIdx.y * 64;
    const int n0 = blockIdx.x * 64;
    const int t  = threadIdx.x;
    const int tx = t & 15, ty = t >> 4;
    const int lr = t >> 5, lc = t & 31;
    float acc[4][4];
#pragma unroll
    for (int q = 0; q < 4; q++)
#pragma unroll
        for (int r = 0; r < 4; r++) acc[q][r] = 0.f;

    for (int k0 = 0; k0 < DIMM; k0 += 32) {
        __syncthreads();
#pragma unroll
        for (int r = 0; r < 8; r++) {
            int row = lr + r * 8;
            Wt[row][lc] = w_in[(size_t)(o0 + row) * DIMM + k0 + lc];
            Xt[row][lc] = x[((size_t)b * NTOK + n0 + row) * DIMM + k0 + lc];
        }
        __syncthreads();
#pragma unroll
        for (int k = 0; k < 32; k++) {
            float wv[4], xv[4];
#pragma unroll
            for (int q = 0; q < 4; q++) { wv[q] = Wt[ty + 16 * q][k]; xv[q] = Xt[tx + 16 * q][k]; }
#pragma unroll
            for (int q = 0; q < 4; q++)
#pragma unroll
                for (int r = 0; r < 4; r++) acc[q][r] += wv[q] * xv[r];
        }
    }
#pragma unroll
    for (int q = 0; q < 4; q++) {
        int o = o0 + ty + 16 * q;
        float inv  = g1[o] / sqrtf(v1[o] + EPSB);
        float beta = b1[o] - m1[o] * inv;
#pragma unroll
        for (int r = 0; r < 4; r++) {
            int n = n0 + tx + 16 * r;
            Y[((size_t)b * DIMM + o) * NTOK + n] = acc[q][r] * inv + beta;
        }
    }
}

// ---------------- K2: depthwise 3x3 (SAME) on 32x32, input = xs[s] (+ ys[s-1]) ----------------
__global__ __launch_bounds__(256) void k_dwconv(
    const float* __restrict__ Y,
    const float* __restrict__ w_dw,  // [C][1][3][3]
    float* __restrict__ tmp, int s)
{
    __shared__ float img[34][34];
    const int c = blockIdx.x;
    const int b = blockIdx.y;
    const int t = threadIdx.x;
    for (int i = t; i < 34 * 34; i += 256) (&img[0][0])[i] = 0.f;
    __syncthreads();
    const float* src0 = Y + ((size_t)b * DIMM + s * CC + c) * NTOK;
    const float* src1 = (s >= 2) ? (Y + ((size_t)b * DIMM + (s - 1) * CC + c) * NTOK) : nullptr;
    for (int p = t; p < NTOK; p += 256) {
        float v = src0[p];
        if (src1) v += src1[p];
        img[(p >> 5) + 1][(p & 31) + 1] = v;
    }
    __syncthreads();
    float w[9];
#pragma unroll
    for (int i = 0; i < 9; i++) w[i] = w_dw[c * 9 + i];
    for (int p = t; p < NTOK; p += 256) {
        int yy = p >> 5, xx = p & 31;
        float s0 = 0.f;
#pragma unroll
        for (int ky = 0; ky < 3; ky++)
#pragma unroll
            for (int kx = 0; kx < 3; kx++)
                s0 += img[yy + ky][xx + kx] * w[ky * 3 + kx];
        tmp[((size_t)b * CC + c) * NTOK + p] = s0;
    }
}

// ---------------- K3: pointwise 1x1 GEMM + BN2, writes ys[s] over Y scale-s channels ----------------
__global__ __launch_bounds__(256) void k_pwconv(
    const float* __restrict__ tmp,
    const float* __restrict__ w_pw,  // [C][C]
    const float* __restrict__ g2, const float* __restrict__ b2,
    const float* __restrict__ m2, const float* __restrict__ v2,
    float* __restrict__ Y, int s)
{
    __shared__ float Wt[32][33];
    __shared__ float Tt[32][33];
    const int b  = blockIdx.z;
    const int o0 = blockIdx.y * 32;
    const int n0 = blockIdx.x * 32;
    const int t  = threadIdx.x;
    const int tx = t & 15, ty = t >> 4;
    const int lr = t >> 5, lc = t & 31;
    float acc[2][2] = {{0.f, 0.f}, {0.f, 0.f}};
    for (int k0 = 0; k0 < CC; k0 += 32) {
        __syncthreads();
#pragma unroll
        for (int r = 0; r < 4; r++) {
            int row = lr + r * 8;
            Wt[row][lc] = w_pw[(size_t)(o0 + row) * CC + k0 + lc];
            Tt[row][lc] = tmp[((size_t)b * CC + k0 + row) * NTOK + n0 + lc];
        }
        __syncthreads();
#pragma unroll
        for (int k = 0; k < 32; k++) {
            float wv[2] = {Wt[ty][k], Wt[ty + 16][k]};
            float tv[2] = {Tt[k][tx], Tt[k][tx + 16]};
            acc[0][0] += wv[0] * tv[0]; acc[0][1] += wv[0] * tv[1];
            acc[1][0] += wv[1] * tv[0]; acc[1][1] += wv[1] * tv[1];
        }
    }
#pragma unroll
    for (int q = 0; q < 2; q++) {
        int o = o0 + ty + 16 * q;
        float inv  = g2[o] / sqrtf(v2[o] + EPSB);
        float beta = b2[o] - m2[o] * inv;
#pragma unroll
        for (int r = 0; r < 2; r++) {
            int n = n0 + tx + 16 * r;
            Y[((size_t)b * DIMM + s * CC + o) * NTOK + n] = acc[q][r] * inv + beta;
        }
    }
}

// ---------------- K4: attention per (b, scale, head), flash-style online softmax ----------------
// Q[d][n] = Y[b][s*128+h*32+d][n]; att = softmax(SCALE * Q^T Q); O[b][n][s*128+h*32+d] = att @ Q^T
__global__ __launch_bounds__(256) void k_attn(
    const float* __restrict__ Y,
    float* __restrict__ O)
{
    __shared__ float Qi[DD][32];        // [d][ii], pre-scaled by SCALE
    __shared__ float Qj[DD][TJ + 1];    // [d][j]
    __shared__ float P[32][TJ + 1];     // scores -> probs
    __shared__ float mrow[32], lsum[32], arow[32];
    const int ib = blockIdx.x;          // i-block (32 rows)
    const int g  = blockIdx.y;          // 128 groups
    const int b = g >> 4, s = (g >> 2) & 3, h = g & 3;
    const int cb = s * CC + h * DD;
    const float* Q = Y + ((size_t)b * DIMM + cb) * NTOK;
    const int i0 = ib * 32;
    const int t  = threadIdx.x;

    for (int idx = t; idx < DD * 32; idx += 256) {
        int d = idx >> 5, ii = idx & 31;
        Qi[d][ii] = Q[d * NTOK + i0 + ii] * SCALE_ATT;
    }
    if (t < 32) { mrow[t] = -INFINITY; lsum[t] = 0.f; }
    float o_acc[4] = {0.f, 0.f, 0.f, 0.f};
    const int d_o = t & 31, igO = t >> 5;   // O-phase: thread -> (d, 4 consecutive i)
    const int jg = t & 31, igS = t >> 5;    // S-phase: thread -> (4 i, 4 j strided 32)
    const int rr = t >> 3, oct = t & 7;     // reductions: 8 lanes per row
    __syncthreads();

    for (int j0 = 0; j0 < NTOK; j0 += TJ) {
        __syncthreads();  // prior tile's consumers done with Qj/P
#pragma unroll
        for (int k = 0; k < (DD * TJ) / 256; k++) {
            int idx = t + k * 256;
            Qj[idx >> 7][idx & (TJ - 1)] = Q[(idx >> 7) * NTOK + j0 + (idx & (TJ - 1))];
        }
        __syncthreads();
        // S = (SCALE*Qi)^T Qj : 4x4 micro-tile per thread
        float sacc[4][4];
#pragma unroll
        for (int q = 0; q < 4; q++)
#pragma unroll
            for (int jj = 0; jj < 4; jj++) sacc[q][jj] = 0.f;
        for (int d = 0; d < DD; d++) {
            float qi[4], qj[4];
#pragma unroll
            for (int q = 0; q < 4; q++) qi[q] = Qi[d][igS * 4 + q];
#pragma unroll
            for (int jj = 0; jj < 4; jj++) qj[jj] = Qj[d][jg + 32 * jj];
#pragma unroll
            for (int q = 0; q < 4; q++)
#pragma unroll
                for (int jj = 0; jj < 4; jj++) sacc[q][jj] += qi[q] * qj[jj];
        }
#pragma unroll
        for (int q = 0; q < 4; q++)
#pragma unroll
            for (int jj = 0; jj < 4; jj++) P[igS * 4 + q][jg + 32 * jj] = sacc[q][jj];
        __syncthreads();
        // row max over tile (8 lanes/row, 16 elems each, shfl combine)
        {
            float mx = -INFINITY;
#pragma unroll
            for (int jj = 0; jj < TJ / 8; jj++) mx = fmaxf(mx, P[rr][oct * (TJ / 8) + jj]);
            mx = fmaxf(mx, __shfl_xor(mx, 1));
            mx = fmaxf(mx, __shfl_xor(mx, 2));
            mx = fmaxf(mx, __shfl_xor(mx, 4));
            if (oct == 0) {
                float mold = mrow[rr];
                float mnew = fmaxf(mold, mx);
                mrow[rr] = mnew;
                arow[rr] = __expf(mold - mnew);   // 0 on first tile (mold=-inf)
            }
        }
        __syncthreads();
        // exp + row sum
        {
            float mn = mrow[rr];
            float sm = 0.f;
#pragma unroll
            for (int jj = 0; jj < TJ / 8; jj++) {
                int j = oct * (TJ / 8) + jj;
                float e = __expf(P[rr][j] - mn);
                P[rr][j] = e;
                sm += e;
            }
            sm += __shfl_xor(sm, 1);
            sm += __shfl_xor(sm, 2);
            sm += __shfl_xor(sm, 4);
            if (oct == 0) lsum[rr] = lsum[rr] * arow[rr] + sm;
        }
        __syncthreads();
        // O accumulation: o[i][d] += sum_j P[i][j] * Qj[d][j]
        {
#pragma unroll
            for (int q = 0; q < 4; q++) o_acc[q] *= arow[igO * 4 + q];
            for (int j = 0; j < TJ; j++) {
                float qv = Qj[d_o][j];
#pragma unroll
                for (int q = 0; q < 4; q++) o_acc[q] += P[igO * 4 + q][j] * qv;
            }
        }
    }
    __syncthreads();
#pragma unroll
    for (int q = 0; q < 4; q++) {
        int i = igO * 4 + q;
        O[((size_t)b * NTOK + i0 + i) * DIMM + cb + d_o] = o_acc[q] / lsum[i];
    }
}

// ---------------- K5: out-proj GEMM, f32 store (d_out is FLOAT32) ----------------
// out[r][oc] = sum_k O[r][k] * w_out[oc][k],  r = b*N+n
__global__ __launch_bounds__(256) void k_outproj(
    const float* __restrict__ O,
    const float* __restrict__ w_out,
    float* __restrict__ out)
{
    __shared__ float At[64][33];
    __shared__ float Wt[64][33];
    const int r0 = blockIdx.x * 64;   // 8192 rows
    const int o0 = blockIdx.y * 64;   // 512 cols
    const int t  = threadIdx.x;
    const int tx = t & 15, ty = t >> 4;
    const int lr = t >> 5, lc = t & 31;
    float acc[4][4];
#pragma unroll
    for (int q = 0; q < 4; q++)
#pragma unroll
        for (int r = 0; r < 4; r++) acc[q][r] = 0.f;

    for (int k0 = 0; k0 < DIMM; k0 += 32) {
        __syncthreads();
#pragma unroll
        for (int r = 0; r < 8; r++) {
            int row = lr + r * 8;
            At[row][lc] = O[(size_t)(r0 + row) * DIMM + k0 + lc];
            Wt[row][lc] = w_out[(size_t)(o0 + row) * DIMM + k0 + lc];
        }
        __syncthreads();
#pragma unroll
        for (int k = 0; k < 32; k++) {
            float av[4], wv[4];
#pragma unroll
            for (int q = 0; q < 4; q++) { av[q] = At[ty + 16 * q][k]; wv[q] = Wt[tx + 16 * q][k]; }
#pragma unroll
            for (int q = 0; q < 4; q++)
#pragma unroll
                for (int r = 0; r < 4; r++) acc[q][r] += av[q] * wv[r];
        }
    }
#pragma unroll
    for (int q = 0; q < 4; q++)
#pragma unroll
        for (int r = 0; r < 4; r++)
            out[(size_t)(r0 + ty + 16 * q) * DIMM + o0 + tx + 16 * r] = acc[q][r];
}

extern "C" void kernel_launch(void* const* d_in, const int* in_sizes, int n_in,
                              void* d_out, int out_size, void* d_ws, size_t ws_size,
                              hipStream_t stream)
{
    const float* x    = (const float*)d_in[0];
    const float* w_in = (const float*)d_in[1];
    const float* g1   = (const float*)d_in[2];
    const float* b1   = (const float*)d_in[3];
    const float* m1   = (const float*)d_in[4];
    const float* v1   = (const float*)d_in[5];
    const float* wdw  = (const float*)d_in[6];
    const float* wpw  = (const float*)d_in[7];
    const float* g2   = (const float*)d_in[8];
    const float* b2   = (const float*)d_in[9];
    const float* m2   = (const float*)d_in[10];
    const float* v2   = (const float*)d_in[11];
    const float* wout = (const float*)d_in[12];
    float* out = (float*)d_out;

    float* Y   = (float*)d_ws;                       // [8][512][1024] f32, 16 MB
    float* O   = Y + (size_t)BB * DIMM * NTOK;       // [8][1024][512] f32, 16 MB
    float* tmp = O;                                  // [8][128][1024] f32, aliased (disjoint in time)

    k_inconv<<<dim3(16, 8, 8), 256, 0, stream>>>(x, w_in, g1, b1, m1, v1, Y);
    for (int s = 1; s <= 3; s++) {
        k_dwconv<<<dim3(CC, BB), 256, 0, stream>>>(Y, wdw, tmp, s);
        k_pwconv<<<dim3(32, 4, 8), 256, 0, stream>>>(tmp, wpw, g2, b2, m2, v2, Y, s);
    }
    k_attn<<<dim3(32, 128), 256, 0, stream>>>(Y, O);
    k_outproj<<<dim3(128, 8), 256, 0, stream>>>(O, wout, out);
}

// Round 5
// 435.653 us; speedup vs baseline: 1.7975x; 1.7975x over previous
//
#include <hip/hip_runtime.h>
#include <hip/hip_bf16.h>

// MSAttention: Res2Net inconv + 3x(dwconv+pwconv+BN) + per-(scale,head) self-attention + out-proj.
// R5: k_attn rewritten on mfma_f32_16x16x32_bf16 (flash-style online softmax, all-register row
// stats, P via LDS round-trip). Rest identical to the R4 passing version.
// Layouts:
//   Y   f32 [B][512][N]   channel-major
//   O   f32 [B][N][512]   attention output
//   tmp f32 [B][128][N]   dwconv out, aliased on O (disjoint in time)
// ws: 32 MB.

#define DIMM 512
#define NTOK 1024
#define CC   128
#define DD   32
#define BB   8
#define EPSB 1e-5f
#define SCALE_ATT 0.17677669529663687f  // 32^-0.5
#define TJ 128

typedef __attribute__((ext_vector_type(8))) short short8;
typedef __attribute__((ext_vector_type(4))) float f32x4;

__device__ __forceinline__ unsigned short f2bf(float f) {
    unsigned int x = __float_as_uint(f);
    unsigned int r = x + 0x7fffu + ((x >> 16) & 1u);   // RNE, finite inputs
    return (unsigned short)(r >> 16);
}

// ---------------- K1: inconv (1x1) GEMM + BN1 ----------------
__global__ __launch_bounds__(256) void k_inconv(
    const float* __restrict__ x, const float* __restrict__ w_in,
    const float* __restrict__ g1, const float* __restrict__ b1,
    const float* __restrict__ m1, const float* __restrict__ v1,
    float* __restrict__ Y)
{
    __shared__ float Wt[64][33];
    __shared__ float Xt[64][33];
    const int b  = blockIdx.z;
    const int o0 = blockIdx.y * 64;
    const int n0 = blockIdx.x * 64;
    const int t  = threadIdx.x;
    const int tx = t & 15, ty = t >> 4;
    const int lr = t >> 5, lc = t & 31;
    float acc[4][4];
#pragma unroll
    for (int q = 0; q < 4; q++)
#pragma unroll
        for (int r = 0; r < 4; r++) acc[q][r] = 0.f;

    for (int k0 = 0; k0 < DIMM; k0 += 32) {
        __syncthreads();
#pragma unroll
        for (int r = 0; r < 8; r++) {
            int row = lr + r * 8;
            Wt[row][lc] = w_in[(size_t)(o0 + row) * DIMM + k0 + lc];
            Xt[row][lc] = x[((size_t)b * NTOK + n0 + row) * DIMM + k0 + lc];
        }
        __syncthreads();
#pragma unroll
        for (int k = 0; k < 32; k++) {
            float wv[4], xv[4];
#pragma unroll
            for (int q = 0; q < 4; q++) { wv[q] = Wt[ty + 16 * q][k]; xv[q] = Xt[tx + 16 * q][k]; }
#pragma unroll
            for (int q = 0; q < 4; q++)
#pragma unroll
                for (int r = 0; r < 4; r++) acc[q][r] += wv[q] * xv[r];
        }
    }
#pragma unroll
    for (int q = 0; q < 4; q++) {
        int o = o0 + ty + 16 * q;
        float inv  = g1[o] / sqrtf(v1[o] + EPSB);
        float beta = b1[o] - m1[o] * inv;
#pragma unroll
        for (int r = 0; r < 4; r++) {
            int n = n0 + tx + 16 * r;
            Y[((size_t)b * DIMM + o) * NTOK + n] = acc[q][r] * inv + beta;
        }
    }
}

// ---------------- K2: depthwise 3x3 ----------------
__global__ __launch_bounds__(256) void k_dwconv(
    const float* __restrict__ Y, const float* __restrict__ w_dw,
    float* __restrict__ tmp, int s)
{
    __shared__ float img[34][34];
    const int c = blockIdx.x;
    const int b = blockIdx.y;
    const int t = threadIdx.x;
    for (int i = t; i < 34 * 34; i += 256) (&img[0][0])[i] = 0.f;
    __syncthreads();
    const float* src0 = Y + ((size_t)b * DIMM + s * CC + c) * NTOK;
    const float* src1 = (s >= 2) ? (Y + ((size_t)b * DIMM + (s - 1) * CC + c) * NTOK) : nullptr;
    for (int p = t; p < NTOK; p += 256) {
        float v = src0[p];
        if (src1) v += src1[p];
        img[(p >> 5) + 1][(p & 31) + 1] = v;
    }
    __syncthreads();
    float w[9];
#pragma unroll
    for (int i = 0; i < 9; i++) w[i] = w_dw[c * 9 + i];
    for (int p = t; p < NTOK; p += 256) {
        int yy = p >> 5, xx = p & 31;
        float s0 = 0.f;
#pragma unroll
        for (int ky = 0; ky < 3; ky++)
#pragma unroll
            for (int kx = 0; kx < 3; kx++)
                s0 += img[yy + ky][xx + kx] * w[ky * 3 + kx];
        tmp[((size_t)b * CC + c) * NTOK + p] = s0;
    }
}

// ---------------- K3: pointwise 1x1 GEMM + BN2 ----------------
__global__ __launch_bounds__(256) void k_pwconv(
    const float* __restrict__ tmp, const float* __restrict__ w_pw,
    const float* __restrict__ g2, const float* __restrict__ b2,
    const float* __restrict__ m2, const float* __restrict__ v2,
    float* __restrict__ Y, int s)
{
    __shared__ float Wt[32][33];
    __shared__ float Tt[32][33];
    const int b  = blockIdx.z;
    const int o0 = blockIdx.y * 32;
    const int n0 = blockIdx.x * 32;
    const int t  = threadIdx.x;
    const int tx = t & 15, ty = t >> 4;
    const int lr = t >> 5, lc = t & 31;
    float acc[2][2] = {{0.f, 0.f}, {0.f, 0.f}};
    for (int k0 = 0; k0 < CC; k0 += 32) {
        __syncthreads();
#pragma unroll
        for (int r = 0; r < 4; r++) {
            int row = lr + r * 8;
            Wt[row][lc] = w_pw[(size_t)(o0 + row) * CC + k0 + lc];
            Tt[row][lc] = tmp[((size_t)b * CC + k0 + row) * NTOK + n0 + lc];
        }
        __syncthreads();
#pragma unroll
        for (int k = 0; k < 32; k++) {
            float wv[2] = {Wt[ty][k], Wt[ty + 16][k]};
            float tv[2] = {Tt[k][tx], Tt[k][tx + 16]};
            acc[0][0] += wv[0] * tv[0]; acc[0][1] += wv[0] * tv[1];
            acc[1][0] += wv[1] * tv[0]; acc[1][1] += wv[1] * tv[1];
        }
    }
#pragma unroll
    for (int q = 0; q < 2; q++) {
        int o = o0 + ty + 16 * q;
        float inv  = g2[o] / sqrtf(v2[o] + EPSB);
        float beta = b2[o] - m2[o] * inv;
#pragma unroll
        for (int r = 0; r < 2; r++) {
            int n = n0 + tx + 16 * r;
            Y[((size_t)b * DIMM + s * CC + o) * NTOK + n] = acc[q][r] * inv + beta;
        }
    }
}

// ---------------- K4: MFMA flash attention ----------------
// grid.x = 1024: blk>>3 = group g (b,s,h), blk&7 = 128-row i-tile. 4 waves; wave owns 32 i-rows.
// S = (scale*Q)^T Q via mfma 16x16x32 bf16 (A-frags in regs); online softmax on C-layout
// accumulators (row=quad*4+reg, col=lane&15) with shfl_xor 1/2/4/8; P -> bf16 -> LDS -> PV MFMA.
__global__ __launch_bounds__(256) void k_attn(
    const float* __restrict__ Y,
    float* __restrict__ O)
{
    __shared__ __align__(16) unsigned short Qj [32][136];   // [d][j]  (PV B-frags)
    __shared__ __align__(16) unsigned short Qjt[128][40];   // [j][d]  (S  B-frags)
    __shared__ __align__(16) unsigned short P  [128][136];  // [i][j]  (PV A-frags)

    const int blk = blockIdx.x;
    const int g = blk >> 3, ib = blk & 7;
    const int b = g >> 4, s = (g >> 2) & 3, h = g & 3;
    const int cb = s * CC + h * DD;
    const float* Q = Y + ((size_t)b * DIMM + cb) * NTOK;
    const int t = threadIdx.x;
    const int wid = t >> 6, lane = t & 63;
    const int l16 = lane & 15, quad = lane >> 4;
    const int i0 = ib * 128;        // group-row base of this block
    const int iw = wid * 32;        // block-local wave row base

    // A-fragments: A[m=lane&15][k=quad*8+jj] = bf16(scale * Q[d=k][i]) — resident all kernel
    short8 afrag[2];
#pragma unroll
    for (int iblk = 0; iblk < 2; iblk++) {
        int i = i0 + iw + iblk * 16 + l16;
#pragma unroll
        for (int jj = 0; jj < 8; jj++) {
            float v = Q[(size_t)(quad * 8 + jj) * NTOK + i] * SCALE_ATT;
            afrag[iblk][jj] = (short)f2bf(v);
        }
    }

    float m_st[2][4], l_st[2][4];
    f32x4 oacc[2][2];
#pragma unroll
    for (int iblk = 0; iblk < 2; iblk++)
#pragma unroll
        for (int r = 0; r < 4; r++) {
            m_st[iblk][r] = -INFINITY; l_st[iblk][r] = 0.f;
            oacc[iblk][0][r] = 0.f;    oacc[iblk][1][r] = 0.f;
        }

    for (int j0 = 0; j0 < NTOK; j0 += TJ) {
        __syncthreads();   // prior tile's PV reads of Qj done
        // stage Q j-tile as bf16, both layouts
#pragma unroll
        for (int k = 0; k < 16; k++) {
            int idx = k * 256 + t;
            int d = idx >> 7, j = idx & 127;
            unsigned short u = f2bf(Q[(size_t)d * NTOK + j0 + j]);
            Qj[d][j] = u;
            Qjt[j][d] = u;
        }
        __syncthreads();

        // S-tile: 32 (i) x 128 (j) per wave
        f32x4 sacc[2][8];
        const f32x4 zero4 = {0.f, 0.f, 0.f, 0.f};
#pragma unroll
        for (int jb = 0; jb < 8; jb++) {
            short8 bf_ = *(const short8*)&Qjt[jb * 16 + l16][quad * 8];
            sacc[0][jb] = __builtin_amdgcn_mfma_f32_16x16x32_bf16(afrag[0], bf_, zero4, 0, 0, 0);
            sacc[1][jb] = __builtin_amdgcn_mfma_f32_16x16x32_bf16(afrag[1], bf_, zero4, 0, 0, 0);
        }

        // online softmax on accumulators; write P (bf16) — wave-private rows, no barrier needed
#pragma unroll
        for (int iblk = 0; iblk < 2; iblk++) {
#pragma unroll
            for (int r = 0; r < 4; r++) {
                float mx = sacc[iblk][0][r];
#pragma unroll
                for (int jb = 1; jb < 8; jb++) mx = fmaxf(mx, sacc[iblk][jb][r]);
                mx = fmaxf(mx, __shfl_xor(mx, 1));
                mx = fmaxf(mx, __shfl_xor(mx, 2));
                mx = fmaxf(mx, __shfl_xor(mx, 4));
                mx = fmaxf(mx, __shfl_xor(mx, 8));
                float mo = m_st[iblk][r];
                float mn = fmaxf(mo, mx);
                float al = __expf(mo - mn);        // 0 on first tile
                m_st[iblk][r] = mn;
                int prow = iw + iblk * 16 + quad * 4 + r;
                float rs = 0.f;
#pragma unroll
                for (int jb = 0; jb < 8; jb++) {
                    float p = __expf(sacc[iblk][jb][r] - mn);
                    rs += p;
                    P[prow][jb * 16 + l16] = f2bf(p);
                }
                rs += __shfl_xor(rs, 1);
                rs += __shfl_xor(rs, 2);
                rs += __shfl_xor(rs, 4);
                rs += __shfl_xor(rs, 8);
                l_st[iblk][r] = l_st[iblk][r] * al + rs;
                oacc[iblk][0][r] *= al;
                oacc[iblk][1][r] *= al;
            }
        }

        // PV: O[32 i][32 d] += P[32][128] * V[128][32], V[j][d] = Q[d][j] = Qj[d][j]
#pragma unroll
        for (int iblk = 0; iblk < 2; iblk++) {
#pragma unroll
            for (int kc = 0; kc < 4; kc++) {
                short8 ap = *(const short8*)&P[iw + iblk * 16 + l16][kc * 32 + quad * 8];
                short8 b0 = *(const short8*)&Qj[l16][kc * 32 + quad * 8];
                short8 b1 = *(const short8*)&Qj[16 + l16][kc * 32 + quad * 8];
                oacc[iblk][0] = __builtin_amdgcn_mfma_f32_16x16x32_bf16(ap, b0, oacc[iblk][0], 0, 0, 0);
                oacc[iblk][1] = __builtin_amdgcn_mfma_f32_16x16x32_bf16(ap, b1, oacc[iblk][1], 0, 0, 0);
            }
        }
    }

    // epilogue: O[b][i][cb+d] = oacc / l
#pragma unroll
    for (int iblk = 0; iblk < 2; iblk++)
#pragma unroll
        for (int dblk = 0; dblk < 2; dblk++)
#pragma unroll
            for (int r = 0; r < 4; r++) {
                int i = i0 + iw + iblk * 16 + quad * 4 + r;
                int d = dblk * 16 + l16;
                O[((size_t)b * NTOK + i) * DIMM + cb + d] = oacc[iblk][dblk][r] / l_st[iblk][r];
            }
}

// ---------------- K5: out-proj GEMM, f32 store ----------------
__global__ __launch_bounds__(256) void k_outproj(
    const float* __restrict__ O,
    const float* __restrict__ w_out,
    float* __restrict__ out)
{
    __shared__ float At[64][33];
    __shared__ float Wt[64][33];
    const int r0 = blockIdx.x * 64;
    const int o0 = blockIdx.y * 64;
    const int t  = threadIdx.x;
    const int tx = t & 15, ty = t >> 4;
    const int lr = t >> 5, lc = t & 31;
    float acc[4][4];
#pragma unroll
    for (int q = 0; q < 4; q++)
#pragma unroll
        for (int r = 0; r < 4; r++) acc[q][r] = 0.f;

    for (int k0 = 0; k0 < DIMM; k0 += 32) {
        __syncthreads();
#pragma unroll
        for (int r = 0; r < 8; r++) {
            int row = lr + r * 8;
            At[row][lc] = O[(size_t)(r0 + row) * DIMM + k0 + lc];
            Wt[row][lc] = w_out[(size_t)(o0 + row) * DIMM + k0 + lc];
        }
        __syncthreads();
#pragma unroll
        for (int k = 0; k < 32; k++) {
            float av[4], wv[4];
#pragma unroll
            for (int q = 0; q < 4; q++) { av[q] = At[ty + 16 * q][k]; wv[q] = Wt[tx + 16 * q][k]; }
#pragma unroll
            for (int q = 0; q < 4; q++)
#pragma unroll
                for (int r = 0; r < 4; r++) acc[q][r] += av[q] * wv[r];
        }
    }
#pragma unroll
    for (int q = 0; q < 4; q++)
#pragma unroll
        for (int r = 0; r < 4; r++)
            out[(size_t)(r0 + ty + 16 * q) * DIMM + o0 + tx + 16 * r] = acc[q][r];
}

extern "C" void kernel_launch(void* const* d_in, const int* in_sizes, int n_in,
                              void* d_out, int out_size, void* d_ws, size_t ws_size,
                              hipStream_t stream)
{
    const float* x    = (const float*)d_in[0];
    const float* w_in = (const float*)d_in[1];
    const float* g1   = (const float*)d_in[2];
    const float* b1   = (const float*)d_in[3];
    const float* m1   = (const float*)d_in[4];
    const float* v1   = (const float*)d_in[5];
    const float* wdw  = (const float*)d_in[6];
    const float* wpw  = (const float*)d_in[7];
    const float* g2   = (const float*)d_in[8];
    const float* b2   = (const float*)d_in[9];
    const float* m2   = (const float*)d_in[10];
    const float* v2   = (const float*)d_in[11];
    const float* wout = (const float*)d_in[12];
    float* out = (float*)d_out;

    float* Y   = (float*)d_ws;                       // [8][512][1024] f32, 16 MB
    float* O   = Y + (size_t)BB * DIMM * NTOK;       // [8][1024][512] f32, 16 MB
    float* tmp = O;                                  // aliased (disjoint in time)

    k_inconv<<<dim3(16, 8, 8), 256, 0, stream>>>(x, w_in, g1, b1, m1, v1, Y);
    for (int s = 1; s <= 3; s++) {
        k_dwconv<<<dim3(CC, BB), 256, 0, stream>>>(Y, wdw, tmp, s);
        k_pwconv<<<dim3(32, 4, 8), 256, 0, stream>>>(tmp, wpw, g2, b2, m2, v2, Y, s);
    }
    k_attn<<<dim3(1024), 256, 0, stream>>>(Y, O);
    k_outproj<<<dim3(128, 8), 256, 0, stream>>>(O, wout, out);
}

// Round 6
// 303.834 us; speedup vs baseline: 2.5774x; 1.4339x over previous
//
#include <hip/hip_runtime.h>
#include <hip/hip_bf16.h>

// MSAttention on MI355X. R6: both 512-K GEMMs (inconv, outproj) moved to bf16 MFMA
// (128x128 tile, BK=64, m92-style padded-LDS staging); fused f32->bf16 prepass for
// x/w_in/w_out; attention epilogue writes O as bf16. k_attn/k_dwconv/k_pwconv unchanged.
// ws (25 MB):
//   Y     f32  [8][512][1024] @0        16 MB
//   SHARE 8 MB region @16MB, time-shared (strictly sequential lifetimes):
//         xb  bf16 [8192][512] (cvt -> inconv)   then
//         tmp f32  [8][128][1024] (dwconv -> pwconv)  then
//         Ob  bf16 [8192][512] (attn -> outproj)
//   wb_in  bf16 [512][512] @24MB   512 KB  (persists)
//   wb_out bf16 [512][512] @24.5MB 512 KB  (persists)

#define DIMM 512
#define NTOK 1024
#define CC   128
#define DD   32
#define BB   8
#define EPSB 1e-5f
#define SCALE_ATT 0.17677669529663687f  // 32^-0.5
#define TJ 128

typedef __attribute__((ext_vector_type(8))) short short8;
typedef __attribute__((ext_vector_type(4))) float f32x4;

__device__ __forceinline__ unsigned short f2bf(float f) {
    unsigned int x = __float_as_uint(f);
    unsigned int r = x + 0x7fffu + ((x >> 16) & 1u);   // RNE, finite inputs
    return (unsigned short)(r >> 16);
}

// ---------------- K0: fused f32->bf16 convert (x, w_in, w_out) ----------------
#define CVT_N0 (BB * NTOK * DIMM)     // x: 4194304
#define CVT_N1 (DIMM * DIMM)          // w_in: 262144
#define CVT_TOT4 ((CVT_N0 + 2 * CVT_N1) / 4)
__global__ __launch_bounds__(256) void k_cvt3(
    const float* __restrict__ x, const float* __restrict__ wi, const float* __restrict__ wo,
    unsigned short* __restrict__ xb, unsigned short* __restrict__ wib, unsigned short* __restrict__ wob)
{
    int idx = blockIdx.x * 256 + threadIdx.x;
    if (idx >= CVT_TOT4) return;
    int e = idx * 4;
    const float* src; unsigned short* dst; int off;
    if (e < CVT_N0)                { src = x;  dst = xb;  off = e; }
    else if (e < CVT_N0 + CVT_N1)  { src = wi; dst = wib; off = e - CVT_N0; }
    else                           { src = wo; dst = wob; off = e - CVT_N0 - CVT_N1; }
    float4 v = *(const float4*)&src[off];
    ushort4 u = { f2bf(v.x), f2bf(v.y), f2bf(v.z), f2bf(v.w) };
    *(ushort4*)&dst[off] = u;
}

// ---------------- K1: inconv GEMM (MFMA bf16) + BN1 ----------------
// Y[b][o][n] = BN1( sum_c w_in[o][c] * x[r=b*1024+n][c] );  A=Wb (m=o), B=Xb (n=r)
__global__ __launch_bounds__(256) void k_mm_in(
    const unsigned short* __restrict__ Wb,   // [512][512] bf16
    const unsigned short* __restrict__ Xb,   // [8192][512] bf16
    const float* __restrict__ g1, const float* __restrict__ b1,
    const float* __restrict__ m1, const float* __restrict__ v1,
    float* __restrict__ Y)
{
    __shared__ __align__(16) unsigned short As[128][72];   // [o-local][k], +8 pad
    __shared__ __align__(16) unsigned short Bs[128][72];   // [r-local][k]
    const int r0 = blockIdx.x * 128;
    const int o0 = blockIdx.y * 128;
    const int b  = r0 >> 10, nloc0 = r0 & 1023;
    const int t = threadIdx.x, wid = t >> 6, lane = t & 63;
    const int l16 = lane & 15, quad = lane >> 4;
    const int wm = (wid >> 1) * 64, wn = (wid & 1) * 64;

    f32x4 acc[4][4];
#pragma unroll
    for (int i = 0; i < 4; i++)
#pragma unroll
        for (int j = 0; j < 4; j++) acc[i][j] = (f32x4){0.f, 0.f, 0.f, 0.f};

    for (int k0 = 0; k0 < DIMM; k0 += 64) {
        __syncthreads();
#pragma unroll
        for (int q = 0; q < 4; q++) {
            int flat = q * 256 + t;              // 0..1023 ushort8-chunks
            int row = flat >> 3, c8 = flat & 7;
            *(short8*)&As[row][c8 * 8] = *(const short8*)&Wb[(size_t)(o0 + row) * DIMM + k0 + c8 * 8];
            *(short8*)&Bs[row][c8 * 8] = *(const short8*)&Xb[(size_t)(r0 + row) * DIMM + k0 + c8 * 8];
        }
        __syncthreads();
#pragma unroll
        for (int kk = 0; kk < 2; kk++) {
            short8 af[4], bf_[4];
#pragma unroll
            for (int i = 0; i < 4; i++) af[i]  = *(const short8*)&As[wm + i * 16 + l16][kk * 32 + quad * 8];
#pragma unroll
            for (int j = 0; j < 4; j++) bf_[j] = *(const short8*)&Bs[wn + j * 16 + l16][kk * 32 + quad * 8];
#pragma unroll
            for (int i = 0; i < 4; i++)
#pragma unroll
                for (int j = 0; j < 4; j++)
                    acc[i][j] = __builtin_amdgcn_mfma_f32_16x16x32_bf16(af[i], bf_[j], acc[i][j], 0, 0, 0);
        }
    }
    // epilogue: C row = o (quad*4+reg), col = r (l16) -> Y[b][o][n] n-contig
#pragma unroll
    for (int i = 0; i < 4; i++)
#pragma unroll
        for (int r = 0; r < 4; r++) {
            int o = o0 + wm + i * 16 + quad * 4 + r;
            float inv  = g1[o] / sqrtf(v1[o] + EPSB);
            float beta = b1[o] - m1[o] * inv;
#pragma unroll
            for (int j = 0; j < 4; j++) {
                int n = nloc0 + wn + j * 16 + l16;
                Y[((size_t)b * DIMM + o) * NTOK + n] = acc[i][j][r] * inv + beta;
            }
        }
}

// ---------------- K2: depthwise 3x3 (unchanged) ----------------
__global__ __launch_bounds__(256) void k_dwconv(
    const float* __restrict__ Y, const float* __restrict__ w_dw,
    float* __restrict__ tmp, int s)
{
    __shared__ float img[34][34];
    const int c = blockIdx.x;
    const int b = blockIdx.y;
    const int t = threadIdx.x;
    for (int i = t; i < 34 * 34; i += 256) (&img[0][0])[i] = 0.f;
    __syncthreads();
    const float* src0 = Y + ((size_t)b * DIMM + s * CC + c) * NTOK;
    const float* src1 = (s >= 2) ? (Y + ((size_t)b * DIMM + (s - 1) * CC + c) * NTOK) : nullptr;
    for (int p = t; p < NTOK; p += 256) {
        float v = src0[p];
        if (src1) v += src1[p];
        img[(p >> 5) + 1][(p & 31) + 1] = v;
    }
    __syncthreads();
    float w[9];
#pragma unroll
    for (int i = 0; i < 9; i++) w[i] = w_dw[c * 9 + i];
    for (int p = t; p < NTOK; p += 256) {
        int yy = p >> 5, xx = p & 31;
        float s0 = 0.f;
#pragma unroll
        for (int ky = 0; ky < 3; ky++)
#pragma unroll
            for (int kx = 0; kx < 3; kx++)
                s0 += img[yy + ky][xx + kx] * w[ky * 3 + kx];
        tmp[((size_t)b * CC + c) * NTOK + p] = s0;
    }
}

// ---------------- K3: pointwise 1x1 GEMM + BN2 (unchanged) ----------------
__global__ __launch_bounds__(256) void k_pwconv(
    const float* __restrict__ tmp, const float* __restrict__ w_pw,
    const float* __restrict__ g2, const float* __restrict__ b2,
    const float* __restrict__ m2, const float* __restrict__ v2,
    float* __restrict__ Y, int s)
{
    __shared__ float Wt[32][33];
    __shared__ float Tt[32][33];
    const int b  = blockIdx.z;
    const int o0 = blockIdx.y * 32;
    const int n0 = blockIdx.x * 32;
    const int t  = threadIdx.x;
    const int tx = t & 15, ty = t >> 4;
    const int lr = t >> 5, lc = t & 31;
    float acc[2][2] = {{0.f, 0.f}, {0.f, 0.f}};
    for (int k0 = 0; k0 < CC; k0 += 32) {
        __syncthreads();
#pragma unroll
        for (int r = 0; r < 4; r++) {
            int row = lr + r * 8;
            Wt[row][lc] = w_pw[(size_t)(o0 + row) * CC + k0 + lc];
            Tt[row][lc] = tmp[((size_t)b * CC + k0 + row) * NTOK + n0 + lc];
        }
        __syncthreads();
#pragma unroll
        for (int k = 0; k < 32; k++) {
            float wv[2] = {Wt[ty][k], Wt[ty + 16][k]};
            float tv[2] = {Tt[k][tx], Tt[k][tx + 16]};
            acc[0][0] += wv[0] * tv[0]; acc[0][1] += wv[0] * tv[1];
            acc[1][0] += wv[1] * tv[0]; acc[1][1] += wv[1] * tv[1];
        }
    }
#pragma unroll
    for (int q = 0; q < 2; q++) {
        int o = o0 + ty + 16 * q;
        float inv  = g2[o] / sqrtf(v2[o] + EPSB);
        float beta = b2[o] - m2[o] * inv;
#pragma unroll
        for (int r = 0; r < 2; r++) {
            int n = n0 + tx + 16 * r;
            Y[((size_t)b * DIMM + s * CC + o) * NTOK + n] = acc[q][r] * inv + beta;
        }
    }
}

// ---------------- K4: MFMA flash attention (epilogue now bf16) ----------------
__global__ __launch_bounds__(256) void k_attn(
    const float* __restrict__ Y,
    unsigned short* __restrict__ Ob)
{
    __shared__ __align__(16) unsigned short Qj [32][136];   // [d][j]  (PV B-frags)
    __shared__ __align__(16) unsigned short Qjt[128][40];   // [j][d]  (S  B-frags)
    __shared__ __align__(16) unsigned short P  [128][136];  // [i][j]  (PV A-frags)

    const int blk = blockIdx.x;
    const int g = blk >> 3, ib = blk & 7;
    const int b = g >> 4, s = (g >> 2) & 3, h = g & 3;
    const int cb = s * CC + h * DD;
    const float* Q = Y + ((size_t)b * DIMM + cb) * NTOK;
    const int t = threadIdx.x;
    const int wid = t >> 6, lane = t & 63;
    const int l16 = lane & 15, quad = lane >> 4;
    const int i0 = ib * 128;
    const int iw = wid * 32;

    short8 afrag[2];
#pragma unroll
    for (int iblk = 0; iblk < 2; iblk++) {
        int i = i0 + iw + iblk * 16 + l16;
#pragma unroll
        for (int jj = 0; jj < 8; jj++) {
            float v = Q[(size_t)(quad * 8 + jj) * NTOK + i] * SCALE_ATT;
            afrag[iblk][jj] = (short)f2bf(v);
        }
    }

    float m_st[2][4], l_st[2][4];
    f32x4 oacc[2][2];
#pragma unroll
    for (int iblk = 0; iblk < 2; iblk++)
#pragma unroll
        for (int r = 0; r < 4; r++) {
            m_st[iblk][r] = -INFINITY; l_st[iblk][r] = 0.f;
            oacc[iblk][0][r] = 0.f;    oacc[iblk][1][r] = 0.f;
        }

    for (int j0 = 0; j0 < NTOK; j0 += TJ) {
        __syncthreads();
#pragma unroll
        for (int k = 0; k < 16; k++) {
            int idx = k * 256 + t;
            int d = idx >> 7, j = idx & 127;
            unsigned short u = f2bf(Q[(size_t)d * NTOK + j0 + j]);
            Qj[d][j] = u;
            Qjt[j][d] = u;
        }
        __syncthreads();

        f32x4 sacc[2][8];
        const f32x4 zero4 = {0.f, 0.f, 0.f, 0.f};
#pragma unroll
        for (int jb = 0; jb < 8; jb++) {
            short8 bf_ = *(const short8*)&Qjt[jb * 16 + l16][quad * 8];
            sacc[0][jb] = __builtin_amdgcn_mfma_f32_16x16x32_bf16(afrag[0], bf_, zero4, 0, 0, 0);
            sacc[1][jb] = __builtin_amdgcn_mfma_f32_16x16x32_bf16(afrag[1], bf_, zero4, 0, 0, 0);
        }

#pragma unroll
        for (int iblk = 0; iblk < 2; iblk++) {
#pragma unroll
            for (int r = 0; r < 4; r++) {
                float mx = sacc[iblk][0][r];
#pragma unroll
                for (int jb = 1; jb < 8; jb++) mx = fmaxf(mx, sacc[iblk][jb][r]);
                mx = fmaxf(mx, __shfl_xor(mx, 1));
                mx = fmaxf(mx, __shfl_xor(mx, 2));
                mx = fmaxf(mx, __shfl_xor(mx, 4));
                mx = fmaxf(mx, __shfl_xor(mx, 8));
                float mo = m_st[iblk][r];
                float mn = fmaxf(mo, mx);
                float al = __expf(mo - mn);
                m_st[iblk][r] = mn;
                int prow = iw + iblk * 16 + quad * 4 + r;
                float rs = 0.f;
#pragma unroll
                for (int jb = 0; jb < 8; jb++) {
                    float p = __expf(sacc[iblk][jb][r] - mn);
                    rs += p;
                    P[prow][jb * 16 + l16] = f2bf(p);
                }
                rs += __shfl_xor(rs, 1);
                rs += __shfl_xor(rs, 2);
                rs += __shfl_xor(rs, 4);
                rs += __shfl_xor(rs, 8);
                l_st[iblk][r] = l_st[iblk][r] * al + rs;
                oacc[iblk][0][r] *= al;
                oacc[iblk][1][r] *= al;
            }
        }

#pragma unroll
        for (int iblk = 0; iblk < 2; iblk++) {
#pragma unroll
            for (int kc = 0; kc < 4; kc++) {
                short8 ap = *(const short8*)&P[iw + iblk * 16 + l16][kc * 32 + quad * 8];
                short8 b0 = *(const short8*)&Qj[l16][kc * 32 + quad * 8];
                short8 b1 = *(const short8*)&Qj[16 + l16][kc * 32 + quad * 8];
                oacc[iblk][0] = __builtin_amdgcn_mfma_f32_16x16x32_bf16(ap, b0, oacc[iblk][0], 0, 0, 0);
                oacc[iblk][1] = __builtin_amdgcn_mfma_f32_16x16x32_bf16(ap, b1, oacc[iblk][1], 0, 0, 0);
            }
        }
    }

#pragma unroll
    for (int iblk = 0; iblk < 2; iblk++)
#pragma unroll
        for (int dblk = 0; dblk < 2; dblk++)
#pragma unroll
            for (int r = 0; r < 4; r++) {
                int i = i0 + iw + iblk * 16 + quad * 4 + r;
                int d = dblk * 16 + l16;
                Ob[((size_t)b * NTOK + i) * DIMM + cb + d] = f2bf(oacc[iblk][dblk][r] / l_st[iblk][r]);
            }
}

// ---------------- K5: out-proj GEMM (MFMA bf16), f32 store ----------------
// out[r][o] = sum_k O[r][k] * w_out[o][k];  A=Ob (m=r), B=Wob (n=o)
__global__ __launch_bounds__(256) void k_mm_out(
    const unsigned short* __restrict__ Oin,  // [8192][512] bf16
    const unsigned short* __restrict__ Wob,  // [512][512] bf16
    float* __restrict__ out)
{
    __shared__ __align__(16) unsigned short As[128][72];   // [r-local][k]
    __shared__ __align__(16) unsigned short Bs[128][72];   // [o-local][k]
    const int r0 = blockIdx.x * 128;
    const int o0 = blockIdx.y * 128;
    const int t = threadIdx.x, wid = t >> 6, lane = t & 63;
    const int l16 = lane & 15, quad = lane >> 4;
    const int wm = (wid >> 1) * 64, wn = (wid & 1) * 64;

    f32x4 acc[4][4];
#pragma unroll
    for (int i = 0; i < 4; i++)
#pragma unroll
        for (int j = 0; j < 4; j++) acc[i][j] = (f32x4){0.f, 0.f, 0.f, 0.f};

    for (int k0 = 0; k0 < DIMM; k0 += 64) {
        __syncthreads();
#pragma unroll
        for (int q = 0; q < 4; q++) {
            int flat = q * 256 + t;
            int row = flat >> 3, c8 = flat & 7;
            *(short8*)&As[row][c8 * 8] = *(const short8*)&Oin[(size_t)(r0 + row) * DIMM + k0 + c8 * 8];
            *(short8*)&Bs[row][c8 * 8] = *(const short8*)&Wob[(size_t)(o0 + row) * DIMM + k0 + c8 * 8];
        }
        __syncthreads();
#pragma unroll
        for (int kk = 0; kk < 2; kk++) {
            short8 af[4], bf_[4];
#pragma unroll
            for (int i = 0; i < 4; i++) af[i]  = *(const short8*)&As[wm + i * 16 + l16][kk * 32 + quad * 8];
#pragma unroll
            for (int j = 0; j < 4; j++) bf_[j] = *(const short8*)&Bs[wn + j * 16 + l16][kk * 32 + quad * 8];
#pragma unroll
            for (int i = 0; i < 4; i++)
#pragma unroll
                for (int j = 0; j < 4; j++)
                    acc[i][j] = __builtin_amdgcn_mfma_f32_16x16x32_bf16(af[i], bf_[j], acc[i][j], 0, 0, 0);
        }
    }
    // C row = r (quad*4+reg), col = o (l16) -> out[r][o] o-contig
#pragma unroll
    for (int i = 0; i < 4; i++)
#pragma unroll
        for (int r = 0; r < 4; r++) {
            int rr = r0 + wm + i * 16 + quad * 4 + r;
#pragma unroll
            for (int j = 0; j < 4; j++) {
                int o = o0 + wn + j * 16 + l16;
                out[(size_t)rr * DIMM + o] = acc[i][j][r];
            }
        }
}

extern "C" void kernel_launch(void* const* d_in, const int* in_sizes, int n_in,
                              void* d_out, int out_size, void* d_ws, size_t ws_size,
                              hipStream_t stream)
{
    const float* x    = (const float*)d_in[0];
    const float* w_in = (const float*)d_in[1];
    const float* g1   = (const float*)d_in[2];
    const float* b1   = (const float*)d_in[3];
    const float* m1   = (const float*)d_in[4];
    const float* v1   = (const float*)d_in[5];
    const float* wdw  = (const float*)d_in[6];
    const float* wpw  = (const float*)d_in[7];
    const float* g2   = (const float*)d_in[8];
    const float* b2   = (const float*)d_in[9];
    const float* m2   = (const float*)d_in[10];
    const float* v2   = (const float*)d_in[11];
    const float* wout = (const float*)d_in[12];
    float* out = (float*)d_out;

    char* base = (char*)d_ws;
    float* Y = (float*)base;                                             // 16 MB
    char* share = base + (size_t)16 * 1024 * 1024;                       // 8 MB, time-shared
    unsigned short* xb  = (unsigned short*)share;                        // cvt -> inconv
    float*          tmp = (float*)share;                                 // dwconv -> pwconv
    unsigned short* Ob  = (unsigned short*)share;                        // attn -> outproj
    unsigned short* wib = (unsigned short*)(base + (size_t)24 * 1024 * 1024);          // 512 KB
    unsigned short* wob = (unsigned short*)(base + (size_t)24 * 1024 * 1024 + 524288); // 512 KB

    k_cvt3<<<dim3((CVT_TOT4 + 255) / 256), 256, 0, stream>>>(x, w_in, wout, xb, wib, wob);
    k_mm_in<<<dim3(64, 4), 256, 0, stream>>>(wib, xb, g1, b1, m1, v1, Y);
    for (int s = 1; s <= 3; s++) {
        k_dwconv<<<dim3(CC, BB), 256, 0, stream>>>(Y, wdw, tmp, s);
        k_pwconv<<<dim3(32, 4, 8), 256, 0, stream>>>(tmp, wpw, g2, b2, m2, v2, Y, s);
    }
    k_attn<<<dim3(1024), 256, 0, stream>>>(Y, Ob);
    k_mm_out<<<dim3(64, 4), 256, 0, stream>>>(Ob, wob, out);
}

// Round 7
// 286.789 us; speedup vs baseline: 2.7305x; 1.0594x over previous
//
#include <hip/hip_runtime.h>
#include <hip/hip_bf16.h>

// MSAttention on MI355X. R7: barrier-free MFMA flash attention.
//  - k_prep materializes Q in bf16 twice: Ybt (token-major per group) and Ybc (channel-major).
//  - k_attn: ALL MFMA operand frags are direct 16B global loads (L2-hot, XCD-affine mapping);
//    LDS holds only the wave-private P buffer (C->A layout round-trip); ZERO __syncthreads.
//  - mm kernels convert f32->bf16 during LDS staging (no separate cvt kernel / weight buffers).
// ws layout (exactly 32 MB):
//   @0   Y   f32 [8][512][1024] 16 MB  (mm_in -> convs -> prep)   then Ob bf16 [8192][512] 8 MB
//   @16  tmp f32 4 MB (convs)                                     then Ybc bf16 8 MB (prep out)
//   @24  Ybt bf16 [128][1024][32] 8 MB (prep out)

#define DIMM 512
#define NTOK 1024
#define CC   128
#define DD   32
#define BB   8
#define EPSB 1e-5f
#define SCALE_ATT 0.17677669529663687f   // 32^-0.5
#define K2EXP (SCALE_ATT * 1.4426950408889634f)  // scale * log2(e), folded into exp2
#define TJ 128

typedef __attribute__((ext_vector_type(8))) short short8;
typedef __attribute__((ext_vector_type(4))) float f32x4;

__device__ __forceinline__ unsigned short f2bf(float f) {
    unsigned int x = __float_as_uint(f);
    unsigned int r = x + 0x7fffu + ((x >> 16) & 1u);   // RNE, finite inputs
    return (unsigned short)(r >> 16);
}
__device__ __forceinline__ unsigned int f2bf2(float lo, float hi) {
    return (unsigned int)f2bf(lo) | ((unsigned int)f2bf(hi) << 16);
}

// ---------------- K1: inconv GEMM (MFMA bf16, inline f32->bf16 staging) + BN1 ----------------
// Y[b][o][n] = BN1( sum_c w_in[o][c] * x[r=b*1024+n][c] )
__global__ __launch_bounds__(256) void k_mm_in(
    const float* __restrict__ w_in,   // [512][512]
    const float* __restrict__ x,      // [8192][512]
    const float* __restrict__ g1, const float* __restrict__ b1,
    const float* __restrict__ m1, const float* __restrict__ v1,
    float* __restrict__ Y)
{
    __shared__ __align__(16) unsigned short As[128][72];   // [o-local][k]
    __shared__ __align__(16) unsigned short Bs[128][72];   // [r-local][k]
    const int r0 = blockIdx.x * 128;
    const int o0 = blockIdx.y * 128;
    const int b  = r0 >> 10, nloc0 = r0 & 1023;
    const int t = threadIdx.x, wid = t >> 6, lane = t & 63;
    const int l16 = lane & 15, quad = lane >> 4;
    const int wm = (wid >> 1) * 64, wn = (wid & 1) * 64;

    f32x4 acc[4][4];
#pragma unroll
    for (int i = 0; i < 4; i++)
#pragma unroll
        for (int j = 0; j < 4; j++) acc[i][j] = (f32x4){0.f, 0.f, 0.f, 0.f};

    for (int k0 = 0; k0 < DIMM; k0 += 64) {
        __syncthreads();
#pragma unroll
        for (int it = 0; it < 8; it++) {
            int flat = it * 256 + t;             // 0..2047 float4-chunks
            int row = flat >> 4, c4 = flat & 15;
            float4 w4 = *(const float4*)&w_in[(size_t)(o0 + row) * DIMM + k0 + c4 * 4];
            *(uint2*)&As[row][c4 * 4] = make_uint2(f2bf2(w4.x, w4.y), f2bf2(w4.z, w4.w));
            float4 x4 = *(const float4*)&x[(size_t)(r0 + row) * DIMM + k0 + c4 * 4];
            *(uint2*)&Bs[row][c4 * 4] = make_uint2(f2bf2(x4.x, x4.y), f2bf2(x4.z, x4.w));
        }
        __syncthreads();
#pragma unroll
        for (int kk = 0; kk < 2; kk++) {
            short8 af[4], bf_[4];
#pragma unroll
            for (int i = 0; i < 4; i++) af[i]  = *(const short8*)&As[wm + i * 16 + l16][kk * 32 + quad * 8];
#pragma unroll
            for (int j = 0; j < 4; j++) bf_[j] = *(const short8*)&Bs[wn + j * 16 + l16][kk * 32 + quad * 8];
#pragma unroll
            for (int i = 0; i < 4; i++)
#pragma unroll
                for (int j = 0; j < 4; j++)
                    acc[i][j] = __builtin_amdgcn_mfma_f32_16x16x32_bf16(af[i], bf_[j], acc[i][j], 0, 0, 0);
        }
    }
#pragma unroll
    for (int i = 0; i < 4; i++)
#pragma unroll
        for (int r = 0; r < 4; r++) {
            int o = o0 + wm + i * 16 + quad * 4 + r;
            float inv  = g1[o] / sqrtf(v1[o] + EPSB);
            float beta = b1[o] - m1[o] * inv;
#pragma unroll
            for (int j = 0; j < 4; j++) {
                int n = nloc0 + wn + j * 16 + l16;
                Y[((size_t)b * DIMM + o) * NTOK + n] = acc[i][j][r] * inv + beta;
            }
        }
}

// ---------------- K2: depthwise 3x3 (unchanged) ----------------
__global__ __launch_bounds__(256) void k_dwconv(
    const float* __restrict__ Y, const float* __restrict__ w_dw,
    float* __restrict__ tmp, int s)
{
    __shared__ float img[34][34];
    const int c = blockIdx.x;
    const int b = blockIdx.y;
    const int t = threadIdx.x;
    for (int i = t; i < 34 * 34; i += 256) (&img[0][0])[i] = 0.f;
    __syncthreads();
    const float* src0 = Y + ((size_t)b * DIMM + s * CC + c) * NTOK;
    const float* src1 = (s >= 2) ? (Y + ((size_t)b * DIMM + (s - 1) * CC + c) * NTOK) : nullptr;
    for (int p = t; p < NTOK; p += 256) {
        float v = src0[p];
        if (src1) v += src1[p];
        img[(p >> 5) + 1][(p & 31) + 1] = v;
    }
    __syncthreads();
    float w[9];
#pragma unroll
    for (int i = 0; i < 9; i++) w[i] = w_dw[c * 9 + i];
    for (int p = t; p < NTOK; p += 256) {
        int yy = p >> 5, xx = p & 31;
        float s0 = 0.f;
#pragma unroll
        for (int ky = 0; ky < 3; ky++)
#pragma unroll
            for (int kx = 0; kx < 3; kx++)
                s0 += img[yy + ky][xx + kx] * w[ky * 3 + kx];
        tmp[((size_t)b * CC + c) * NTOK + p] = s0;
    }
}

// ---------------- K3: pointwise 1x1 GEMM + BN2 (unchanged) ----------------
__global__ __launch_bounds__(256) void k_pwconv(
    const float* __restrict__ tmp, const float* __restrict__ w_pw,
    const float* __restrict__ g2, const float* __restrict__ b2,
    const float* __restrict__ m2, const float* __restrict__ v2,
    float* __restrict__ Y, int s)
{
    __shared__ float Wt[32][33];
    __shared__ float Tt[32][33];
    const int b  = blockIdx.z;
    const int o0 = blockIdx.y * 32;
    const int n0 = blockIdx.x * 32;
    const int t  = threadIdx.x;
    const int tx = t & 15, ty = t >> 4;
    const int lr = t >> 5, lc = t & 31;
    float acc[2][2] = {{0.f, 0.f}, {0.f, 0.f}};
    for (int k0 = 0; k0 < CC; k0 += 32) {
        __syncthreads();
#pragma unroll
        for (int r = 0; r < 4; r++) {
            int row = lr + r * 8;
            Wt[row][lc] = w_pw[(size_t)(o0 + row) * CC + k0 + lc];
            Tt[row][lc] = tmp[((size_t)b * CC + k0 + row) * NTOK + n0 + lc];
        }
        __syncthreads();
#pragma unroll
        for (int k = 0; k < 32; k++) {
            float wv[2] = {Wt[ty][k], Wt[ty + 16][k]};
            float tv[2] = {Tt[k][tx], Tt[k][tx + 16]};
            acc[0][0] += wv[0] * tv[0]; acc[0][1] += wv[0] * tv[1];
            acc[1][0] += wv[1] * tv[0]; acc[1][1] += wv[1] * tv[1];
        }
    }
#pragma unroll
    for (int q = 0; q < 2; q++) {
        int o = o0 + ty + 16 * q;
        float inv  = g2[o] / sqrtf(v2[o] + EPSB);
        float beta = b2[o] - m2[o] * inv;
#pragma unroll
        for (int r = 0; r < 2; r++) {
            int n = n0 + tx + 16 * r;
            Y[((size_t)b * DIMM + s * CC + o) * NTOK + n] = acc[q][r] * inv + beta;
        }
    }
}

// ---------------- K3.5: prep — Y f32 -> Ybc (bf16 ch-major) + Ybt (bf16 token-major/group) ----
__global__ __launch_bounds__(256) void k_prep(
    const float* __restrict__ Y,
    unsigned short* __restrict__ Ybc,   // [8][512][1024]
    unsigned short* __restrict__ Ybt)   // [128][1024][32]
{
    __shared__ float T[32][129];
    const int n0 = blockIdx.x * 128;
    const int g  = blockIdx.y;
    const int b = g >> 4, s = (g >> 2) & 3, h = g & 3;
    const int cb = s * CC + h * DD;
    const int t = threadIdx.x;
#pragma unroll
    for (int k = 0; k < 8; k++) {
        int idx = k * 256 + t;            // 0..2047 float2-chunks
        int d = idx >> 6, jp = (idx & 63) * 2;
        float2 v = *(const float2*)&Y[((size_t)b * DIMM + cb + d) * NTOK + n0 + jp];
        T[d][jp] = v.x; T[d][jp + 1] = v.y;
        *(unsigned int*)&Ybc[((size_t)b * DIMM + cb + d) * NTOK + n0 + jp] = f2bf2(v.x, v.y);
    }
    __syncthreads();
#pragma unroll
    for (int k = 0; k < 8; k++) {
        int idx = k * 256 + t;            // 0..2047 d-pair chunks
        int n = idx >> 4, dp = (idx & 15) * 2;
        *(unsigned int*)&Ybt[((size_t)g * NTOK + n0 + n) * DD + dp] = f2bf2(T[dp][n], T[dp + 1][n]);
    }
}

// ---------------- K4: barrier-free MFMA flash attention ----------------
// g = blk & 127 (XCD-affine: same group's 8 i-blocks land on the same XCD), ib = blk >> 7.
// Block = 4 independent waves; wave owns 32 i-rows. All MFMA frags direct from global bf16.
// LDS: wave-private P only (C-layout -> A-layout round-trip). No __syncthreads anywhere.
__global__ __launch_bounds__(256) void k_attn(
    const unsigned short* __restrict__ Ybt,
    const unsigned short* __restrict__ Ybc,
    unsigned short* __restrict__ Ob)
{
    __shared__ __align__(16) unsigned short P[4][32][132];
    const int blk = blockIdx.x;
    const int g = blk & 127, ib = blk >> 7;
    const int b = g >> 4, s = (g >> 2) & 3, h = g & 3;
    const int cb = s * CC + h * DD;
    const unsigned short* Qt = Ybt + (size_t)g * NTOK * DD;          // [token][d]
    const unsigned short* Qc = Ybc + ((size_t)b * DIMM + cb) * NTOK; // [d][token]
    const int t = threadIdx.x;
    const int wid = t >> 6, lane = t & 63;
    const int l16 = lane & 15, quad = lane >> 4;
    const int i0 = ib * 128 + wid * 32;          // wave's first i-row
    unsigned short (*Pw)[132] = P[wid];

    short8 afrag[2];
    afrag[0] = *(const short8*)&Qt[(size_t)(i0 + l16) * DD + quad * 8];
    afrag[1] = *(const short8*)&Qt[(size_t)(i0 + 16 + l16) * DD + quad * 8];

    float m_st[2][4], l_st[2][4];
    f32x4 oacc[2][2];
#pragma unroll
    for (int iblk = 0; iblk < 2; iblk++)
#pragma unroll
        for (int r = 0; r < 4; r++) {
            m_st[iblk][r] = -INFINITY; l_st[iblk][r] = 0.f;
            oacc[iblk][0][r] = 0.f;    oacc[iblk][1][r] = 0.f;
        }
    const f32x4 zero4 = {0.f, 0.f, 0.f, 0.f};

    for (int j0 = 0; j0 < NTOK; j0 += TJ) {
        // S B-frags for this j-tile (token-major), shared by both iblk halves
        short8 bt[8];
#pragma unroll
        for (int jb = 0; jb < 8; jb++)
            bt[jb] = *(const short8*)&Qt[(size_t)(j0 + jb * 16 + l16) * DD + quad * 8];

#pragma unroll
        for (int iblk = 0; iblk < 2; iblk++) {
            f32x4 sacc[8];
#pragma unroll
            for (int jb = 0; jb < 8; jb++)
                sacc[jb] = __builtin_amdgcn_mfma_f32_16x16x32_bf16(afrag[iblk], bt[jb], zero4, 0, 0, 0);

            // online softmax (raw-S domain, exp2 with folded scale)
#pragma unroll
            for (int r = 0; r < 4; r++) {
                float mx = sacc[0][r];
#pragma unroll
                for (int jb = 1; jb < 8; jb++) mx = fmaxf(mx, sacc[jb][r]);
                mx = fmaxf(mx, __shfl_xor(mx, 1));
                mx = fmaxf(mx, __shfl_xor(mx, 2));
                mx = fmaxf(mx, __shfl_xor(mx, 4));
                mx = fmaxf(mx, __shfl_xor(mx, 8));
                float mo = m_st[iblk][r];
                float mn = fmaxf(mo, mx);
                m_st[iblk][r] = mn;
                float mnk = mn * K2EXP;
                float al = exp2f(fmaf(mo, K2EXP, -mnk));   // 0 on first tile
                int prow = iblk * 16 + quad * 4 + r;
                float rs = 0.f;
#pragma unroll
                for (int jb = 0; jb < 8; jb++) {
                    float p = exp2f(fmaf(sacc[jb][r], K2EXP, -mnk));
                    rs += p;
                    Pw[prow][jb * 16 + l16] = f2bf(p);
                }
                rs += __shfl_xor(rs, 1);
                rs += __shfl_xor(rs, 2);
                rs += __shfl_xor(rs, 4);
                rs += __shfl_xor(rs, 8);
                l_st[iblk][r] = l_st[iblk][r] * al + rs;
                oacc[iblk][0][r] *= al;
                oacc[iblk][1][r] *= al;
            }

            // PV: A from Pw (same wave's DS ops are in-order -> no barrier), B from Ybc
#pragma unroll
            for (int kc = 0; kc < 4; kc++) {
                short8 ap = *(const short8*)&Pw[iblk * 16 + l16][kc * 32 + quad * 8];
                short8 b0 = *(const short8*)&Qc[(size_t)l16 * NTOK + j0 + kc * 32 + quad * 8];
                short8 b1 = *(const short8*)&Qc[(size_t)(16 + l16) * NTOK + j0 + kc * 32 + quad * 8];
                oacc[iblk][0] = __builtin_amdgcn_mfma_f32_16x16x32_bf16(ap, b0, oacc[iblk][0], 0, 0, 0);
                oacc[iblk][1] = __builtin_amdgcn_mfma_f32_16x16x32_bf16(ap, b1, oacc[iblk][1], 0, 0, 0);
            }
        }
    }

#pragma unroll
    for (int iblk = 0; iblk < 2; iblk++)
#pragma unroll
        for (int r = 0; r < 4; r++) {
            float invl = 1.f / l_st[iblk][r];
            int i = i0 + iblk * 16 + quad * 4 + r;
#pragma unroll
            for (int dblk = 0; dblk < 2; dblk++) {
                int d = dblk * 16 + l16;
                Ob[((size_t)b * NTOK + i) * DIMM + cb + d] = f2bf(oacc[iblk][dblk][r] * invl);
            }
        }
}

// ---------------- K5: out-proj GEMM (A=Ob bf16 direct, B=w_out f32 inline-cvt), f32 out ----
__global__ __launch_bounds__(256) void k_mm_out(
    const unsigned short* __restrict__ Oin,  // [8192][512] bf16
    const float* __restrict__ w_out,         // [512][512] f32
    float* __restrict__ out)
{
    __shared__ __align__(16) unsigned short As[128][72];
    __shared__ __align__(16) unsigned short Bs[128][72];
    const int r0 = blockIdx.x * 128;
    const int o0 = blockIdx.y * 128;
    const int t = threadIdx.x, wid = t >> 6, lane = t & 63;
    const int l16 = lane & 15, quad = lane >> 4;
    const int wm = (wid >> 1) * 64, wn = (wid & 1) * 64;

    f32x4 acc[4][4];
#pragma unroll
    for (int i = 0; i < 4; i++)
#pragma unroll
        for (int j = 0; j < 4; j++) acc[i][j] = (f32x4){0.f, 0.f, 0.f, 0.f};

    for (int k0 = 0; k0 < DIMM; k0 += 64) {
        __syncthreads();
#pragma unroll
        for (int q = 0; q < 4; q++) {
            int flat = q * 256 + t;               // short8-chunks for A
            int row = flat >> 3, c8 = flat & 7;
            *(short8*)&As[row][c8 * 8] = *(const short8*)&Oin[(size_t)(r0 + row) * DIMM + k0 + c8 * 8];
        }
#pragma unroll
        for (int it = 0; it < 8; it++) {
            int flat = it * 256 + t;              // float4-chunks for B
            int row = flat >> 4, c4 = flat & 15;
            float4 w4 = *(const float4*)&w_out[(size_t)(o0 + row) * DIMM + k0 + c4 * 4];
            *(uint2*)&Bs[row][c4 * 4] = make_uint2(f2bf2(w4.x, w4.y), f2bf2(w4.z, w4.w));
        }
        __syncthreads();
#pragma unroll
        for (int kk = 0; kk < 2; kk++) {
            short8 af[4], bf_[4];
#pragma unroll
            for (int i = 0; i < 4; i++) af[i]  = *(const short8*)&As[wm + i * 16 + l16][kk * 32 + quad * 8];
#pragma unroll
            for (int j = 0; j < 4; j++) bf_[j] = *(const short8*)&Bs[wn + j * 16 + l16][kk * 32 + quad * 8];
#pragma unroll
            for (int i = 0; i < 4; i++)
#pragma unroll
                for (int j = 0; j < 4; j++)
                    acc[i][j] = __builtin_amdgcn_mfma_f32_16x16x32_bf16(af[i], bf_[j], acc[i][j], 0, 0, 0);
        }
    }
#pragma unroll
    for (int i = 0; i < 4; i++)
#pragma unroll
        for (int r = 0; r < 4; r++) {
            int rr = r0 + wm + i * 16 + quad * 4 + r;
#pragma unroll
            for (int j = 0; j < 4; j++) {
                int o = o0 + wn + j * 16 + l16;
                out[(size_t)rr * DIMM + o] = acc[i][j][r];
            }
        }
}

extern "C" void kernel_launch(void* const* d_in, const int* in_sizes, int n_in,
                              void* d_out, int out_size, void* d_ws, size_t ws_size,
                              hipStream_t stream)
{
    const float* x    = (const float*)d_in[0];
    const float* w_in = (const float*)d_in[1];
    const float* g1   = (const float*)d_in[2];
    const float* b1   = (const float*)d_in[3];
    const float* m1   = (const float*)d_in[4];
    const float* v1   = (const float*)d_in[5];
    const float* wdw  = (const float*)d_in[6];
    const float* wpw  = (const float*)d_in[7];
    const float* g2   = (const float*)d_in[8];
    const float* b2   = (const float*)d_in[9];
    const float* m2   = (const float*)d_in[10];
    const float* v2   = (const float*)d_in[11];
    const float* wout = (const float*)d_in[12];
    float* out = (float*)d_out;

    char* base = (char*)d_ws;
    float*          Y   = (float*)base;                                  // 16 MB (dies at prep)
    unsigned short* Ob  = (unsigned short*)base;                         // 8 MB  (attn out, over Y)
    float*          tmp = (float*)(base + (size_t)16 * 1024 * 1024);     // 4 MB  (convs)
    unsigned short* Ybc = (unsigned short*)(base + (size_t)16 * 1024 * 1024); // 8 MB (after tmp dies)
    unsigned short* Ybt = (unsigned short*)(base + (size_t)24 * 1024 * 1024); // 8 MB

    k_mm_in<<<dim3(64, 4), 256, 0, stream>>>(w_in, x, g1, b1, m1, v1, Y);
    for (int s = 1; s <= 3; s++) {
        k_dwconv<<<dim3(CC, BB), 256, 0, stream>>>(Y, wdw, tmp, s);
        k_pwconv<<<dim3(32, 4, 8), 256, 0, stream>>>(tmp, wpw, g2, b2, m2, v2, Y, s);
    }
    k_prep<<<dim3(8, 128), 256, 0, stream>>>(Y, Ybc, Ybt);
    k_attn<<<dim3(1024), 256, 0, stream>>>(Ybt, Ybc, Ob);
    k_mm_out<<<dim3(64, 4), 256, 0, stream>>>(Ob, wout, out);
}